// Round 1
// baseline (739.914 us; speedup 1.0000x reference)
//
#include <hip/hip_runtime.h>

// Problem constants
#define BB 16
#define SS 8192
#define DD 512   // Q_DIM == K_DIM == ATTN_DIM

typedef float  f32x4  __attribute__((ext_vector_type(4)));
typedef __bf16 bf16x8 __attribute__((ext_vector_type(8)));
typedef __bf16 bf16x4 __attribute__((ext_vector_type(4)));

__device__ __forceinline__ void cvt_store_bf4(unsigned short* dst, f32x4 v) {
    bf16x4 o;
    o.x = (__bf16)v.x; o.y = (__bf16)v.y; o.z = (__bf16)v.z; o.w = (__bf16)v.w;
    *(bf16x4*)dst = o;   // 8-byte LDS store
}

__device__ __forceinline__ float tanh_fast(float x) {
    float e2 = __expf(2.0f * x);
    return 1.0f - 2.0f / (e2 + 1.0f);   // -> +/-1 correctly as e2 -> inf/0
}

// ---------------------------------------------------------------------------
// Kernel 1: blocks 0..63: WkT_f = bf16(Wk^T) in MFMA-fragment order:
//   element (n,k) -> WkT_f[ ((g*16 + j)*64 + lane)*8 + d ]
//   g=n>>4, ml=n&15, j=k>>5, quad=(k>>3)&3, d=k&7, lane=quad*16+ml
//   => each wave B-load (fixed g,j) reads a CONTIGUOUS 1 KB block.
// blocks 64..95: qproj = query @ Wq (fp32), one output per thread
// ---------------------------------------------------------------------------
__global__ __launch_bounds__(256) void prep_kernel(
    const float* __restrict__ query, const float* __restrict__ Wq,
    const float* __restrict__ Wk, float* __restrict__ qproj,
    unsigned short* __restrict__ WkT_f)
{
    __shared__ __bf16 lt[64][65];
    const int bid = blockIdx.x, t = threadIdx.x;
    if (bid < 64) {                        // 8x8 grid of 64x64 (k,n) tiles
        const int k0 = (bid >> 3) * 64, n0 = (bid & 7) * 64;
#pragma unroll
        for (int rep = 0; rep < 4; ++rep) {       // coalesced read
            const int k = rep * 16 + (t >> 4), n = (t & 15) * 4;
            f32x4 vv = *(const f32x4*)&Wk[(size_t)(k0 + k) * DD + n0 + n];
            lt[k][n] = (__bf16)vv.x; lt[k][n + 1] = (__bf16)vv.y;
            lt[k][n + 2] = (__bf16)vv.z; lt[k][n + 3] = (__bf16)vv.w;
        }
        __syncthreads();
        // write fragment-major: thread = (g_loc = t>>6, lane = t&63)
        const int g_loc = t >> 6, lane = t & 63;
        const int ml = lane & 15, quad = lane >> 4;
        const int g = (bid & 7) * 4 + g_loc;
#pragma unroll
        for (int j_loc = 0; j_loc < 2; ++j_loc) {
            const int j = (bid >> 3) * 2 + j_loc;
            bf16x8 o;
#pragma unroll
            for (int d = 0; d < 8; ++d)
                o[d] = lt[j_loc * 32 + quad * 8 + d][g_loc * 16 + ml];
            *(bf16x8*)&WkT_f[((size_t)((g * 16 + j) * 64 + lane)) * 8] = o;
        }
    } else {                               // qproj: 8192 outputs, one per thread
        const int idx = (bid - 64) * 256 + t;
        const int b = idx >> 9;
        const int n = idx & 511;
        const float* q  = query + b * DD;
        const float* wp = Wq + n;
        float acc = 0.0f;
#pragma unroll 8
        for (int k = 0; k < DD; ++k)
            acc = fmaf(q[k], wp[(size_t)k * DD], acc);
        qproj[b * DD + n] = acc;
    }
}

// ---------------------------------------------------------------------------
// K-half: MFMA on one 32KB half-tile (8 j-steps) while staging the NEXT
// half-tile's 8 f32x4 loads (two 4-deep reg batches, issue-early/write-late).
// Staging vmcnt waits piggyback on the younger B-fragment loads inside the
// MFMA cluster, so HBM latency hides under compute. One barrier per half.
// ---------------------------------------------------------------------------
__device__ __forceinline__ void k_half(
    f32x4 (&acc)[4][4], const unsigned short* __restrict__ ksrc,
    const unsigned short* __restrict__ wfbh,
    const float* __restrict__ stage_src, unsigned short* __restrict__ stage_dst,
    const int sbase, const bool do_stage, const int lane)
{
#pragma unroll
    for (int q = 0; q < 2; ++q) {
        f32x4 kst[4];
        if (do_stage) {
#pragma unroll
            for (int j = 0; j < 4; ++j)            // issue early
                kst[j] = *(const f32x4*)(stage_src + (q * 4 + j) * 32);
        }
#pragma unroll
        for (int jj = 0; jj < 4; ++jj) {
            const int j = q * 4 + jj;
            bf16x8 af[4];
#pragma unroll
            for (int i = 0; i < 4; ++i)
                af[i] = *(const bf16x8*)&ksrc[j * 2048 + (i * 64 + lane) * 8];
#pragma unroll
            for (int jn = 0; jn < 4; ++jn) {
                bf16x8 bfr = *(const bf16x8*)(wfbh + ((jn * 16 + j) << 9));
#pragma unroll
                for (int i = 0; i < 4; ++i)
                    acc[i][jn] = __builtin_amdgcn_mfma_f32_16x16x32_bf16(af[i], bfr, acc[i][jn], 0, 0, 0);
            }
        }
        if (do_stage) {
#pragma unroll
            for (int j = 0; j < 4; ++j)            // write late
                cvt_store_bf4(&stage_dst[(q * 4 + j) * 2048 + sbase], kst[j]);
        }
    }
    __syncthreads();
}

// ---------------------------------------------------------------------------
// Kernel 2 (fused, persistent): 512 blocks x 512 threads; block owns 4
// consecutive 64-row chunks of one b. Key tile double-buffered as two 32KB
// k-halves: h0 always in ks[0], h1 in ks[1]. While computing half g, half
// g+1 streams from HBM -> regs -> LDS, so HBM demand is continuous instead
// of phase-locked bursts.
// ---------------------------------------------------------------------------
__global__ __launch_bounds__(512, 4) void fused_kernel(
    const float* __restrict__ keys, const unsigned short* __restrict__ WkT_f,
    const float* __restrict__ qproj, const float* __restrict__ vvec,
    const int* __restrict__ mask, float* __restrict__ e_ws,
    float* __restrict__ cpart, float2* __restrict__ ml_ws)
{
    __shared__ unsigned short ks[2][8 * 2048];    // 2 x 32 KB half-tiles
    __shared__ float sm_part[8][64];
    __shared__ float w_sh[64];
    __shared__ f32x4 red[3][128];

    const int tid  = threadIdx.x;
    const int w    = tid >> 6;        // wave 0..7
    const int lane = tid & 63;
    const int ml   = lane & 15;
    const int quad = lane >> 4;
    const int bid  = blockIdx.x;
    const int b    = bid >> 5;        // 32 blocks per batch
    const int c0   = (bid & 31) << 2; // first of 4 chunks

    // staging thread mapping (same fragment-major layout as before)
    const int m  = tid >> 3;          // s-row 0..63
    const int q8 = tid & 7;
    const int it = m >> 4;
    const int sq = q8 >> 1;
    const int j0q = (q8 & 1) * 4;
    const int sbase = it * 512 + ((m & 15) + 16 * sq) * 8 + j0q;
    const float* krow0 = keys + ((size_t)(b * SS + c0 * 64 + m)) * DD + q8 * 4;

    const unsigned short* wfb = WkT_f + (size_t)w * 32768 + lane * 8;

    // --- prologue: stage chunk c0 half 0 into ks[0] ---
    {
        f32x4 kst[8];
#pragma unroll
        for (int j = 0; j < 8; ++j) kst[j] = *(const f32x4*)(krow0 + j * 32);
#pragma unroll
        for (int j = 0; j < 8; ++j) cvt_store_bf4(&ks[0][j * 2048 + sbase], kst[j]);
    }
    __syncthreads();

#pragma unroll 1
    for (int t = 0; t < 4; ++t) {
        const int c  = c0 + t;
        const int s0 = c << 6;
        const float* krow = krow0 + (size_t)t * 32768;   // this chunk's rows

        // prefetch mask word for the stats phase (hides its load latency)
        int mk = 0;
        if (tid < 64) mk = mask[(size_t)b * SS + s0 + tid];

        f32x4 acc[4][4];
#pragma unroll
        for (int i = 0; i < 4; ++i)
#pragma unroll
            for (int jn = 0; jn < 4; ++jn) acc[i][jn] = (f32x4){0.f, 0.f, 0.f, 0.f};

        // half0 compute from ks[0]; stage this chunk's half1 -> ks[1]
        k_half(acc, ks[0], wfb,        krow + 256,   ks[1], sbase, true,  lane);
        // half1 compute from ks[1]; stage next chunk's half0 -> ks[0]
        k_half(acc, ks[1], wfb + 4096, krow + 32768, ks[0], sbase, t < 3, lane);

        // --- epilogue: e-partials.  C layout: row = quad*4 + reg, col = ml
        float qv[4], vv[4];
#pragma unroll
        for (int jn = 0; jn < 4; ++jn) {
            const int n = w * 64 + jn * 16 + ml;
            qv[jn] = qproj[b * DD + n];
            vv[jn] = vvec[n];
        }
#pragma unroll
        for (int i = 0; i < 4; ++i) {
#pragma unroll
            for (int r = 0; r < 4; ++r) {
                float s = 0.0f;
#pragma unroll
                for (int jn = 0; jn < 4; ++jn) {
                    float xx = acc[i][jn][r] + qv[jn];
                    s += tanh_fast(xx) * vv[jn];
                }
                s += __shfl_xor(s, 1, 64);
                s += __shfl_xor(s, 2, 64);
                s += __shfl_xor(s, 4, 64);
                s += __shfl_xor(s, 8, 64);
                if (ml == 0) sm_part[w][i * 16 + quad * 4 + r] = s;
            }
        }
        __syncthreads();

        // block-local softmax stats (one wave: tid < 64, one s-row each)
        if (tid < 64) {
            float e = sm_part[0][tid] + sm_part[1][tid] + sm_part[2][tid] + sm_part[3][tid]
                    + sm_part[4][tid] + sm_part[5][tid] + sm_part[6][tid] + sm_part[7][tid];
            if (mk == 0) e = -3.402823466e38f;
            e_ws[(size_t)b * SS + s0 + tid] = e;
            float mx = e;
#pragma unroll
            for (int off = 32; off >= 1; off >>= 1) mx = fmaxf(mx, __shfl_xor(mx, off, 64));
            float wv = (mk == 0) ? 0.0f : __expf(e - mx);
            float l  = wv;
#pragma unroll
            for (int off = 32; off >= 1; off >>= 1) l += __shfl_xor(l, off, 64);
            w_sh[tid] = wv;
            if (tid == 0) ml_ws[b * 128 + c] = make_float2(mx, l);
        }
        __syncthreads();

        // context partial: c[n] = sum_{s in 64} w_s * keys[s][n] (L2/L3-hot)
        const int n4 = (tid & 127) << 2;
        const int sh = tid >> 7;                    // 0..3, 16 s-rows each
        const float* kctx = keys + ((size_t)(b * SS + s0 + sh * 16)) * DD + n4;
        f32x4 cacc = (f32x4){0.f, 0.f, 0.f, 0.f};
#pragma unroll 8
        for (int sI = 0; sI < 16; ++sI) {
            float wgt = w_sh[sh * 16 + sI];
            f32x4 kv  = *(const f32x4*)(kctx + (size_t)sI * DD);
            cacc += kv * wgt;
        }
        if (sh) red[sh - 1][tid & 127] = cacc;
        __syncthreads();
        if (sh == 0) {
            cacc += red[0][tid] + red[1][tid] + red[2][tid];
            *(f32x4*)(cpart + ((size_t)(b * 128 + c)) * 512 + n4) = cacc;
        }
    }
}

// ---------------------------------------------------------------------------
// Kernel 3: finalize.
//  blocks 0..15:    c[b][n] = (sum_i cpart[b][i][n]*exp(m_i-M)) / L
//  blocks 16..143:  a[b][s] = exp(e[b][s]-M)/L   (1024 s per block)
// ---------------------------------------------------------------------------
__global__ __launch_bounds__(256) void finalize_kernel(
    const float* __restrict__ e_ws, const float* __restrict__ cpart,
    const float2* __restrict__ ml_ws, float* __restrict__ out)
{
    __shared__ float rm[4], rs[4];
    __shared__ float sc_sh[128];
    __shared__ float cred[4][512];
    const int bid = blockIdx.x, t = threadIdx.x;
    const int b = (bid < 16) ? bid : ((bid - 16) >> 3);

    // global M, L over this b's 128 chunk stats
    float mi = -3.402823466e38f, li = 0.0f;
    if (t < 128) { float2 p = ml_ws[b * 128 + t]; mi = p.x; li = p.y; }
    float mr = mi;
#pragma unroll
    for (int off = 32; off >= 1; off >>= 1) mr = fmaxf(mr, __shfl_xor(mr, off, 64));
    if ((t & 63) == 0) rm[t >> 6] = mr;
    __syncthreads();
    const float M = fmaxf(fmaxf(rm[0], rm[1]), fmaxf(rm[2], rm[3]));
    float si = (t < 128) ? li * __expf(mi - M) : 0.0f;
#pragma unroll
    for (int off = 32; off >= 1; off >>= 1) si += __shfl_xor(si, off, 64);
    if ((t & 63) == 0) rs[t >> 6] = si;
    __syncthreads();
    const float L = rs[0] + rs[1] + rs[2] + rs[3];
    const float invL = 1.0f / L;

    if (bid < 16) {
        if (t < 128) sc_sh[t] = __expf(ml_ws[b * 128 + t].x - M);
        __syncthreads();
        // 4 waves split the 128 i-chunks; lane l covers n = 8l..8l+8
        const int w2 = t >> 6, l = t & 63;
        float pa[8] = {0.f, 0.f, 0.f, 0.f, 0.f, 0.f, 0.f, 0.f};
#pragma unroll 4
        for (int i = w2 * 32; i < w2 * 32 + 32; ++i) {
            const float sc = sc_sh[i];
            const float* cp = cpart + ((size_t)(b * 128 + i)) * 512 + l * 8;
#pragma unroll
            for (int c = 0; c < 8; ++c) pa[c] = fmaf(cp[c], sc, pa[c]);
        }
#pragma unroll
        for (int c = 0; c < 8; ++c) cred[w2][l * 8 + c] = pa[c];
        __syncthreads();
#pragma unroll
        for (int rep = 0; rep < 2; ++rep) {
            const int n = t + rep * 256;
            out[b * DD + n] = (cred[0][n] + cred[1][n] + cred[2][n] + cred[3][n]) * invL;
        }
    } else {
        const int chunk8 = (bid - 16) & 7;
        const float* ep = e_ws + (size_t)b * SS + chunk8 * 1024;
        float* ap = out + BB * DD + (size_t)b * SS + chunk8 * 1024;
#pragma unroll
        for (int r = 0; r < 4; ++r) {
            float e = ep[t + 256 * r];
            ap[t + 256 * r] = __expf(e - M) * invL;
        }
    }
}

// ---------------------------------------------------------------------------
extern "C" void kernel_launch(void* const* d_in, const int* in_sizes, int n_in,
                              void* d_out, int out_size, void* d_ws, size_t ws_size,
                              hipStream_t stream)
{
    const float* query = (const float*)d_in[0];
    const float* keys  = (const float*)d_in[1];
    const int*   mask  = (const int*)  d_in[2];
    const float* Wq    = (const float*)d_in[3];
    const float* Wk    = (const float*)d_in[4];
    const float* v     = (const float*)d_in[5];
    float* out = (float*)d_out;

    // workspace layout
    float*          qproj = (float*)d_ws;                                     // 32 KB
    unsigned short* WkT_f = (unsigned short*)((char*)d_ws + 32768);           // 512 KB
    float*          e_ws  = (float*)((char*)d_ws + 32768 + 524288);           // 512 KB
    float*          cpart = (float*)((char*)d_ws + 32768 + 2 * 524288);       // 4 MB
    float2*         ml_ws = (float2*)((char*)d_ws + 32768 + 2 * 524288 + 4194304); // 16 KB

    prep_kernel    <<<96, 256, 0, stream>>>(query, Wq, Wk, qproj, WkT_f);
    fused_kernel   <<<512, 512, 0, stream>>>(keys, WkT_f, qproj, v, mask,
                                             e_ws, cpart, ml_ws);
    finalize_kernel<<<16 + 128, 256, 0, stream>>>(e_ws, cpart, ml_ws, out);
}

// Round 2
// 458.464 us; speedup vs baseline: 1.6139x; 1.6139x over previous
//
#include <hip/hip_runtime.h>

// Problem constants
#define BB 16
#define SS 8192
#define DD 512   // Q_DIM == K_DIM == ATTN_DIM

typedef float  f32x4  __attribute__((ext_vector_type(4)));
typedef __bf16 bf16x8 __attribute__((ext_vector_type(8)));
typedef __bf16 bf16x4 __attribute__((ext_vector_type(4)));

__device__ __forceinline__ void cvt_store_bf4(unsigned short* dst, f32x4 v) {
    bf16x4 o;
    o.x = (__bf16)v.x; o.y = (__bf16)v.y; o.z = (__bf16)v.z; o.w = (__bf16)v.w;
    *(bf16x4*)dst = o;   // 8-byte LDS store
}

__device__ __forceinline__ float tanh_fast(float x) {
    float e2 = __expf(2.0f * x);
    return 1.0f - 2.0f / (e2 + 1.0f);   // -> +/-1 correctly as e2 -> inf/0
}

// ---------------------------------------------------------------------------
// Kernel 1: blocks 0..63: WkT_f = bf16(Wk^T) in MFMA-fragment order:
//   element (n,k) -> WkT_f[ ((g*16 + j)*64 + lane)*8 + d ]
//   g=n>>4, ml=n&15, j=k>>5, quad=(k>>3)&3, d=k&7, lane=quad*16+ml
//   => each wave B-load (fixed g,j) reads a CONTIGUOUS 1 KB block.
// blocks 64..95: qproj = query @ Wq (fp32), one output per thread
// ---------------------------------------------------------------------------
__global__ __launch_bounds__(256) void prep_kernel(
    const float* __restrict__ query, const float* __restrict__ Wq,
    const float* __restrict__ Wk, float* __restrict__ qproj,
    unsigned short* __restrict__ WkT_f)
{
    __shared__ __bf16 lt[64][65];
    const int bid = blockIdx.x, t = threadIdx.x;
    if (bid < 64) {                        // 8x8 grid of 64x64 (k,n) tiles
        const int k0 = (bid >> 3) * 64, n0 = (bid & 7) * 64;
#pragma unroll
        for (int rep = 0; rep < 4; ++rep) {       // coalesced read
            const int k = rep * 16 + (t >> 4), n = (t & 15) * 4;
            f32x4 vv = *(const f32x4*)&Wk[(size_t)(k0 + k) * DD + n0 + n];
            lt[k][n] = (__bf16)vv.x; lt[k][n + 1] = (__bf16)vv.y;
            lt[k][n + 2] = (__bf16)vv.z; lt[k][n + 3] = (__bf16)vv.w;
        }
        __syncthreads();
        // write fragment-major: thread = (g_loc = t>>6, lane = t&63)
        const int g_loc = t >> 6, lane = t & 63;
        const int ml = lane & 15, quad = lane >> 4;
        const int g = (bid & 7) * 4 + g_loc;
#pragma unroll
        for (int j_loc = 0; j_loc < 2; ++j_loc) {
            const int j = (bid >> 3) * 2 + j_loc;
            bf16x8 o;
#pragma unroll
            for (int d = 0; d < 8; ++d)
                o[d] = lt[j_loc * 32 + quad * 8 + d][g_loc * 16 + ml];
            *(bf16x8*)&WkT_f[((size_t)((g * 16 + j) * 64 + lane)) * 8] = o;
        }
    } else {                               // qproj: 8192 outputs, one per thread
        const int idx = (bid - 64) * 256 + t;
        const int b = idx >> 9;
        const int n = idx & 511;
        const float* q  = query + b * DD;
        const float* wp = Wq + n;
        float acc = 0.0f;
#pragma unroll 8
        for (int k = 0; k < DD; ++k)
            acc = fmaf(q[k], wp[(size_t)k * DD], acc);
        qproj[b * DD + n] = acc;
    }
}

// ---------------------------------------------------------------------------
// Kernel 2 (fused): scores + block-local softmax stats + context partial.
// 512 threads / 8 waves; wave w owns n-slice [64w, 64w+64).
// Staging: 8 batched in-flight f32x4 loads -> cvt -> LDS (fragment-major).
// K-loop barrier-free: A from LDS, B from L2-resident WkT_f (contiguous 1KB).
// Context phase reads the bf16 key tile from LDS (keys hit HBM exactly once).
// ---------------------------------------------------------------------------
__global__ __launch_bounds__(512, 4) void fused_kernel(
    const float* __restrict__ keys, const unsigned short* __restrict__ WkT_f,
    const float* __restrict__ qproj, const float* __restrict__ vvec,
    const int* __restrict__ mask, float* __restrict__ e_ws,
    float* __restrict__ cpart, float2* __restrict__ ml_ws)
{
    __shared__ unsigned short ksA[16 * 2048];     // [j][i-tile][lane][8] = 64 KB
    __shared__ float sm_part[8][64];
    __shared__ float w_sh[64];
    __shared__ f32x4 red[3][128];

    const int tid  = threadIdx.x;
    const int w    = tid >> 6;        // wave 0..7
    const int lane = tid & 63;
    const int ml   = lane & 15;
    const int quad = lane >> 4;
    const int bid  = blockIdx.x;
    const int b    = bid >> 7;
    const int chunk = bid & 127;
    const int s0   = chunk << 6;

    // prefetch mask word for the stats phase (hides its load latency)
    int mk = 0;
    if (tid < 64) mk = mask[(size_t)b * SS + s0 + tid];

    // --- stage keys tile (64 rows x 512 k) fp32 -> bf16, fragment-major ---
    // thread t: row m = t>>3, float4 #(t&7) of each 32-k chunk (one per j)
    const int m  = tid >> 3;
    const int q8 = tid & 7;
    const float* krow = keys + ((size_t)(b * SS + s0 + m)) * DD + q8 * 4;
    const int it = m >> 4;
    const int sq = q8 >> 1;
    const int j0 = (q8 & 1) * 4;
    const int base = it * 512 + ((m & 15) + 16 * sq) * 8 + j0;
    {
        f32x4 kst[8];
#pragma unroll
        for (int h = 0; h < 2; ++h) {
#pragma unroll
            for (int j = 0; j < 8; ++j)            // 8 independent loads in flight
                kst[j] = __builtin_nontemporal_load(
                             (const f32x4*)(krow + (h * 8 + j) * 32));
#pragma unroll
            for (int j = 0; j < 8; ++j)
                cvt_store_bf4(&ksA[(h * 8 + j) * 2048 + base], kst[j]);
        }
    }
    __syncthreads();

    // --- barrier-free K loop; B contiguous per-wave from WkT_f ---
    const unsigned short* wfb = WkT_f + (size_t)w * 32768 + lane * 8;

    f32x4 acc[4][4];
#pragma unroll
    for (int i = 0; i < 4; ++i)
#pragma unroll
        for (int jn = 0; jn < 4; ++jn) acc[i][jn] = (f32x4){0.f, 0.f, 0.f, 0.f};

#pragma unroll 4
    for (int j = 0; j < 16; ++j) {
        bf16x8 af[4];
#pragma unroll
        for (int i = 0; i < 4; ++i)
            af[i] = *(const bf16x8*)&ksA[j * 2048 + (i * 64 + lane) * 8];
#pragma unroll
        for (int jn = 0; jn < 4; ++jn) {
            bf16x8 bfr = *(const bf16x8*)(wfb + ((jn * 16 + j) << 9));
#pragma unroll
            for (int i = 0; i < 4; ++i)
                acc[i][jn] = __builtin_amdgcn_mfma_f32_16x16x32_bf16(af[i], bfr, acc[i][jn], 0, 0, 0);
        }
    }

    // epilogue: e-partials.  C layout: row = quad*4 + reg, col = ml
    float qv[4], vv[4];
#pragma unroll
    for (int jn = 0; jn < 4; ++jn) {
        const int n = w * 64 + jn * 16 + ml;
        qv[jn] = qproj[b * DD + n];
        vv[jn] = vvec[n];
    }
#pragma unroll
    for (int i = 0; i < 4; ++i) {
#pragma unroll
        for (int r = 0; r < 4; ++r) {
            float s = 0.0f;
#pragma unroll
            for (int jn = 0; jn < 4; ++jn) {
                float xx = acc[i][jn][r] + qv[jn];
                s += tanh_fast(xx) * vv[jn];
            }
            s += __shfl_xor(s, 1, 64);
            s += __shfl_xor(s, 2, 64);
            s += __shfl_xor(s, 4, 64);
            s += __shfl_xor(s, 8, 64);
            if (ml == 0) sm_part[w][i * 16 + quad * 4 + r] = s;
        }
    }
    __syncthreads();

    // block-local softmax stats (one wave: tid < 64, each thread one s-row)
    if (tid < 64) {
        float e = sm_part[0][tid] + sm_part[1][tid] + sm_part[2][tid] + sm_part[3][tid]
                + sm_part[4][tid] + sm_part[5][tid] + sm_part[6][tid] + sm_part[7][tid];
        if (mk == 0) e = -3.402823466e38f;
        e_ws[(size_t)b * SS + s0 + tid] = e;
        float mx = e;
#pragma unroll
        for (int off = 32; off >= 1; off >>= 1) mx = fmaxf(mx, __shfl_xor(mx, off, 64));
        float wv = (mk == 0) ? 0.0f : __expf(e - mx);
        float l  = wv;
#pragma unroll
        for (int off = 32; off >= 1; off >>= 1) l += __shfl_xor(l, off, 64);
        w_sh[tid] = wv;
        if (tid == 0) ml_ws[b * 128 + chunk] = make_float2(mx, l);
    }
    __syncthreads();

    // context partial from the LDS bf16 tile: c[n] = sum_s w_s * keys[s][n].
    // keys[s][n] lives at ksA[jq*2048 + (s>>4)*512 + (s&15)*8 + qd*128 + d],
    // n = jq*32 + qd*8 + d.  Per-lane s-rotation spreads bank groups (~2-way).
    const int l   = tid & 127;
    const int sh  = tid >> 7;                   // 0..3, 16 s-rows each
    const int n4  = l << 2;
    const int jq  = l >> 3;
    const int qd  = (l >> 1) & 3;
    const int d0  = (l & 1) * 4;
    const int cbase = jq * 2048 + sh * 512 + qd * 128 + d0;
    const int rot   = (l & 15) + (l >> 3);
    f32x4 cacc = (f32x4){0.f, 0.f, 0.f, 0.f};
#pragma unroll
    for (int p = 0; p < 16; ++p) {
        const int sI = (p + rot) & 15;
        bf16x4 kv = *(const bf16x4*)&ksA[cbase + sI * 8];
        const float wgt = w_sh[sh * 16 + sI];
        cacc.x += wgt * (float)kv.x;
        cacc.y += wgt * (float)kv.y;
        cacc.z += wgt * (float)kv.z;
        cacc.w += wgt * (float)kv.w;
    }
    if (sh) red[sh - 1][l] = cacc;
    __syncthreads();
    if (sh == 0) {
        cacc += red[0][l] + red[1][l] + red[2][l];
        *(f32x4*)(cpart + ((size_t)(b * 128 + chunk)) * 512 + n4) = cacc;
    }
}

// ---------------------------------------------------------------------------
// Kernel 3: finalize.
//  blocks 0..15:    c[b][n] = (sum_i cpart[b][i][n]*exp(m_i-M)) / L
//  blocks 16..143:  a[b][s] = exp(e[b][s]-M)/L   (1024 s per block)
// ---------------------------------------------------------------------------
__global__ __launch_bounds__(256) void finalize_kernel(
    const float* __restrict__ e_ws, const float* __restrict__ cpart,
    const float2* __restrict__ ml_ws, float* __restrict__ out)
{
    __shared__ float rm[4], rs[4];
    __shared__ float sc_sh[128];
    __shared__ float cred[4][512];
    const int bid = blockIdx.x, t = threadIdx.x;
    const int b = (bid < 16) ? bid : ((bid - 16) >> 3);

    // global M, L over this b's 128 chunk stats
    float mi = -3.402823466e38f, li = 0.0f;
    if (t < 128) { float2 p = ml_ws[b * 128 + t]; mi = p.x; li = p.y; }
    float mr = mi;
#pragma unroll
    for (int off = 32; off >= 1; off >>= 1) mr = fmaxf(mr, __shfl_xor(mr, off, 64));
    if ((t & 63) == 0) rm[t >> 6] = mr;
    __syncthreads();
    const float M = fmaxf(fmaxf(rm[0], rm[1]), fmaxf(rm[2], rm[3]));
    float si = (t < 128) ? li * __expf(mi - M) : 0.0f;
#pragma unroll
    for (int off = 32; off >= 1; off >>= 1) si += __shfl_xor(si, off, 64);
    if ((t & 63) == 0) rs[t >> 6] = si;
    __syncthreads();
    const float L = rs[0] + rs[1] + rs[2] + rs[3];
    const float invL = 1.0f / L;

    if (bid < 16) {
        if (t < 128) sc_sh[t] = __expf(ml_ws[b * 128 + t].x - M);
        __syncthreads();
        // 4 waves split the 128 i-chunks; lane l covers n = 8l..8l+8
        const int w2 = t >> 6, l = t & 63;
        float pa[8] = {0.f, 0.f, 0.f, 0.f, 0.f, 0.f, 0.f, 0.f};
#pragma unroll 4
        for (int i = w2 * 32; i < w2 * 32 + 32; ++i) {
            const float sc = sc_sh[i];
            const float* cp = cpart + ((size_t)(b * 128 + i)) * 512 + l * 8;
#pragma unroll
            for (int c = 0; c < 8; ++c) pa[c] = fmaf(cp[c], sc, pa[c]);
        }
#pragma unroll
        for (int c = 0; c < 8; ++c) cred[w2][l * 8 + c] = pa[c];
        __syncthreads();
#pragma unroll
        for (int rep = 0; rep < 2; ++rep) {
            const int n = t + rep * 256;
            out[b * DD + n] = (cred[0][n] + cred[1][n] + cred[2][n] + cred[3][n]) * invL;
        }
    } else {
        const int chunk8 = (bid - 16) & 7;
        const float* ep = e_ws + (size_t)b * SS + chunk8 * 1024;
        float* ap = out + BB * DD + (size_t)b * SS + chunk8 * 1024;
#pragma unroll
        for (int r = 0; r < 4; ++r) {
            float e = ep[t + 256 * r];
            ap[t + 256 * r] = __expf(e - M) * invL;
        }
    }
}

// ---------------------------------------------------------------------------
extern "C" void kernel_launch(void* const* d_in, const int* in_sizes, int n_in,
                              void* d_out, int out_size, void* d_ws, size_t ws_size,
                              hipStream_t stream)
{
    const float* query = (const float*)d_in[0];
    const float* keys  = (const float*)d_in[1];
    const int*   mask  = (const int*)  d_in[2];
    const float* Wq    = (const float*)d_in[3];
    const float* Wk    = (const float*)d_in[4];
    const float* v     = (const float*)d_in[5];
    float* out = (float*)d_out;

    // workspace layout
    float*          qproj = (float*)d_ws;                                     // 32 KB
    unsigned short* WkT_f = (unsigned short*)((char*)d_ws + 32768);           // 512 KB
    float*          e_ws  = (float*)((char*)d_ws + 32768 + 524288);           // 512 KB
    float*          cpart = (float*)((char*)d_ws + 32768 + 2 * 524288);       // 4 MB
    float2*         ml_ws = (float2*)((char*)d_ws + 32768 + 2 * 524288 + 4194304); // 16 KB

    prep_kernel    <<<96, 256, 0, stream>>>(query, Wq, Wk, qproj, WkT_f);
    fused_kernel   <<<BB * (SS / 64), 512, 0, stream>>>(keys, WkT_f, qproj, v, mask,
                                                        e_ws, cpart, ml_ws);
    finalize_kernel<<<16 + 128, 256, 0, stream>>>(e_ws, cpart, ml_ws, out);
}